// Round 15
// baseline (1308.634 us; speedup 1.0000x reference)
//
#include <hip/hip_runtime.h>
#include <hip/hip_bf16.h>
#include <stdint.h>

// Problem constants
#define E_NUM 8
#define D_DIM 512
#define H_DIM 2048
#define NTOK 16384   // B*S = 8*2048

typedef __bf16 bf16;
typedef __bf16 bf16x8 __attribute__((ext_vector_type(8)));
typedef float  f32x4  __attribute__((ext_vector_type(4)));

// GEMM tiling: 256x256 tile, BK=32, 8 waves (2M x 4N), 512 threads.
// r13 post-mortem: v2 counted-vmcnt loop validated (381us) but 1 block/CU lockstep
// leaves 4x headroom (Occ 20%, MfmaUtil 21%). This round: OCCUPANCY. BK 64->32
// halves dbuf LDS to 65KB -> 2 blocks/CU; gemm2 K-split x2 (grid 240->480) so the
// capacity is used. Cross-block wave overlap hides barrier/dep stalls (m114).
// BK=32 row = 64B = 4 slots of 16B; swizzle: stored_slot = ((s+(r>>2))&3)^(r&3)
// -> frag read (16 lanes, fixed quad) hits each bank-pair exactly 2x = free.
#define BM 256
#define BN 256
#define BK 32

// async global->LDS, 16B per lane
typedef __attribute__((address_space(1))) const void* gas_cp;
typedef __attribute__((address_space(3))) void* las_p;
__device__ __forceinline__ void gl_lds16(const void* g, void* l) {
  __builtin_amdgcn_global_load_lds((gas_cp)g, (las_p)l, 16, 0, 0);
}

// Workspace layout (bytes)
static const size_t OFF_FILL = 32;           // 8 ints (per-expert count after fill)
static const size_t OFF_LIST = 128;          // E*NTOK ints = 512KB
static const size_t OFF_XBF  = 1ull << 20;                              // bf16 [NTOK][D] = 16.8MB
static const size_t OFF_W1T  = OFF_XBF + (size_t)NTOK*D_DIM*2;          // bf16 [E][H][D]
static const size_t OFF_W2T  = OFF_W1T + (size_t)E_NUM*H_DIM*D_DIM*2;   // bf16 [E][D][H]
static const size_t OFF_HBUF = OFF_W2T + (size_t)E_NUM*H_DIM*D_DIM*2;   // bf16 [<=34816][H] (256-pad)

// rowbase for expert e, computed from counts (all blocks agree; cnt final at kernel launch)
__device__ __forceinline__ int rowbase_of(const int* cnt, int e) {
  int acc = 0;
  for (int i = 0; i < e; i++) acc += (cnt[i] + BM - 1) & ~(BM - 1);
  return acc;
}

// ---------------- routing: wave-aggregated fill (8 atomics/wave, not 128) ----------------
__global__ void fill_kernel(const int* __restrict__ assign, int* __restrict__ fill,
                            int* __restrict__ lists) {
  int n = blockIdx.x * blockDim.x + threadIdx.x;   // grid exact: no guard (ballot uniformity)
  int lane = threadIdx.x & 63;
  unsigned long long below = ((unsigned long long)1 << lane) - 1;
  int e0 = assign[2*n], e1 = assign[2*n+1];
  #pragma unroll
  for (int e = 0; e < E_NUM; e++) {
    bool h0 = (e0 == e);
    bool h1 = (e1 == e) && (e1 != e0);
    unsigned long long m0 = __ballot(h0);
    unsigned long long m1 = __ballot(h1);
    int c = __popcll(m0) + __popcll(m1);
    if (c > 0) {                                   // wave-uniform
      int leader = __ffsll((long long)(m0 | m1)) - 1;
      int b = 0;
      if (lane == leader) b = atomicAdd(&fill[e], c);
      b = __shfl(b, leader);
      if (h0) lists[e * NTOK + b + __popcll(m0 & below)] = n;
      if (h1) lists[e * NTOK + b + __popcll(m0) + __popcll(m1 & below)] = n;
    }
  }
}

// ---------------- x f32 -> bf16 (un-gathered, one pass) ----------------
__global__ void cvt_x(const float* __restrict__ x, bf16* __restrict__ xbf) {
  size_t i = ((size_t)blockIdx.x * 256 + threadIdx.x) * 8;
  float4 a = *reinterpret_cast<const float4*>(x + i);
  float4 b = *reinterpret_cast<const float4*>(x + i + 4);
  bf16x8 o;
  o[0] = (bf16)a.x; o[1] = (bf16)a.y; o[2] = (bf16)a.z; o[3] = (bf16)a.w;
  o[4] = (bf16)b.x; o[5] = (bf16)b.y; o[6] = (bf16)b.z; o[7] = (bf16)b.w;
  *reinterpret_cast<bf16x8*>(xbf + i) = o;
}

// ---------------- weight transpose + cvt: [E][R][C] f32 -> [E][C][R] bf16 ----------------
__global__ void transpose_cvt(const float* __restrict__ in, bf16* __restrict__ out,
                              int R, int C) {
  __shared__ float tile[32][33];
  int e = blockIdx.z;
  int c0 = blockIdx.x * 32, r0 = blockIdx.y * 32;
  const float* src = in + (size_t)e * R * C;
  bf16* dst = out + (size_t)e * R * C;
  int tx = threadIdx.x, ty = threadIdx.y;  // 32 x 8
  #pragma unroll
  for (int i = 0; i < 32; i += 8)
    tile[ty + i][tx] = src[(size_t)(r0 + ty + i) * C + c0 + tx];
  __syncthreads();
  #pragma unroll
  for (int i = 0; i < 32; i += 8)
    dst[(size_t)(c0 + ty + i) * R + r0 + tx] = (bf16)tile[tx][ty + i];
}

// BK=32 swizzle helpers (derived r14):
//   stored slot for (row r, global chunk s):  ss = ((s + ((r>>2)&3)) & 3) ^ (r & 3)
//   inverse (staging: lane provides ss at row r -> global chunk):
//     s = ((ss ^ (r&3)) - ((r>>2)&3)) & 3
//   read (want chunk quad at row r): slot = ((quad + ((r>>2)&3)) & 3) ^ (r&3)
//   within a 16-row segment: r&3 == lr&3, (r>>2)&3 == (lr>>2)&3 (segments are 16-aligned)

// ---------------- GEMM1: h = relu(Xg @ W1 + b1), bf16 out to hbuf ----------------
// grid: 1D, lin = xcd + 8*(nc + NC1*rbHi); rb = rbHi*8 + xcd; NC1 = 8 chunks over H
#define NC1 (H_DIM / BN)   // 8
__global__ __launch_bounds__(512, 4) void gemm1(
    const bf16* __restrict__ xbf, const bf16* __restrict__ w1t,
    const float* __restrict__ b1, const int* __restrict__ lists,
    const int* __restrict__ cnt, bf16* __restrict__ hbuf) {
  int lin = blockIdx.x;
  int xcd = lin & 7;
  int rem = lin >> 3;
  int nc  = rem & (NC1 - 1);
  int rb  = (rem >> 3) * 8 + xcd;          // rem >> log2(NC1)
  int e   = rb >> 6;                        // rb / 64 (64 row-blocks of 256 per expert)
  int m0  = (rb & 63) * BM;
  int ce  = cnt[e];
  if (m0 >= ce) return;
  int n0 = nc * BN;
  int rbase = rowbase_of(cnt, e);

  __shared__ bf16 xs[2][BM * BK];   // [row][k], row=64B, dbuf 16KB ea -> total 64KB+tok
  __shared__ bf16 bs[2][BN * BK];
  __shared__ int tok[BM];

  int tid = threadIdx.x;
  if (tid < BM) {
    int r = m0 + tid;
    tok[tid] = (r < ce) ? lists[e * NTOK + r] : lists[e * NTOK];
  }
  __syncthreads();

  const bf16* w1e = w1t + (size_t)e * H_DIM * D_DIM + (size_t)n0 * D_DIM;
  int wave = tid >> 6, lane = tid & 63;
  int quad = lane >> 4, l16 = lane & 15;
  int lr = lane >> 2;                        // staging: row within 16-row segment [0,16)
  int ls = lane & 3;                         // staging: stored slot
  int srcoff = ((((ls ^ (lr & 3)) - ((lr >> 2) & 3)) & 3)) * 8;  // global chunk offset (elems)
  int wm = (wave >> 2) * 128, wn = (wave & 3) * 64;   // 2M x 4N wave grid
  int rslot = (((quad + ((l16 >> 2) & 3)) & 3) ^ (l16 & 3)) * 8; // read slot offset (elems)

  // hoisted staging addresses: per wave 2 A segs + 2 B segs, each 16 rows x 32 cols
  const bf16* asrc[2]; const bf16* bsrc[2]; int soff[2];
  #pragma unroll
  for (int i = 0; i < 2; i++) {
    int s = wave * 2 + i;                    // segment in [0,16), rows [16s,16s+16)
    asrc[i] = xbf + (size_t)tok[s * 16 + lr] * D_DIM + srcoff;
    bsrc[i] = w1e + (size_t)(s * 16 + lr) * D_DIM + srcoff;
    soff[i] = s * 512;                       // 16 rows * 32 elems
  }
  auto stage = [&](int buf, int k0) {
    #pragma unroll
    for (int i = 0; i < 2; i++) gl_lds16(asrc[i] + k0, &xs[buf][soff[i]]);
    #pragma unroll
    for (int i = 0; i < 2; i++) gl_lds16(bsrc[i] + k0, &bs[buf][soff[i]]);
  };

  f32x4 acc[8][4] = {};
  const int nk = D_DIM / BK;  // 16
  stage(0, 0);
  stage(1, BK);
  for (int t = 0; t < nk; t++) {
    if (t + 1 < nk) { asm volatile("s_waitcnt vmcnt(4)" ::: "memory"); }
    else            { asm volatile("s_waitcnt vmcnt(0)" ::: "memory"); }
    __builtin_amdgcn_sched_barrier(0);
    __builtin_amdgcn_s_barrier();            // buf[t&1] ready for all waves
    __builtin_amdgcn_sched_barrier(0);
    const bf16* xsc = xs[t & 1];
    const bf16* bsc = bs[t & 1];
    // read + MFMA, UNFENCED: compiler emits fine-grained lgkmcnt interleave (m97)
    __builtin_amdgcn_s_setprio(1);
    {
      bf16x8 bfr[4];
      #pragma unroll
      for (int j = 0; j < 4; j++)
        bfr[j] = *reinterpret_cast<const bf16x8*>(&bsc[(wn + j * 16 + l16) * BK + rslot]);
      #pragma unroll
      for (int i = 0; i < 8; i++) {
        bf16x8 af = *reinterpret_cast<const bf16x8*>(&xsc[(wm + i * 16 + l16) * BK + rslot]);
        #pragma unroll
        for (int j = 0; j < 4; j++)
          acc[i][j] = __builtin_amdgcn_mfma_f32_16x16x32_bf16(af, bfr[j], acc[i][j], 0, 0, 0);
      }
    }
    __builtin_amdgcn_s_setprio(0);
    __builtin_amdgcn_sched_barrier(0);
    __builtin_amdgcn_s_barrier();            // all waves consumed buf[t&1] (reads in regs)
    __builtin_amdgcn_sched_barrier(0);
    if (t + 2 < nk) stage(t & 1, (t + 2) * BK);   // overwrite freed buf; flies across next vmcnt(4)
  }

  bf16* hrow = hbuf + (size_t)(rbase + m0) * H_DIM;
  #pragma unroll
  for (int i = 0; i < 8; i++) {
    int row = wm + i * 16 + quad * 4;
    #pragma unroll
    for (int j = 0; j < 4; j++) {
      int col = n0 + wn + j * 16 + l16;
      float bias = b1[e * H_DIM + col];
      #pragma unroll
      for (int r = 0; r < 4; r++) {
        float v = acc[i][j][r] + bias;
        v = v > 0.f ? v : 0.f;
        hrow[(size_t)(row + r) * H_DIM + col] = (bf16)v;
      }
    }
  }
}

// ---------------- GEMM2: out += 0.5*(h @ W2 + b2), scattered fp32 atomicAdd ----------------
// K-split x2: kh in {0,1} covers K-half [kh*1024, kh*1024+1024); grid 480 active -> ~2/CU
#define NC2 (D_DIM / BN)   // 2
#define KSPLIT 2
#define KHALF (H_DIM / KSPLIT)  // 1024
__global__ __launch_bounds__(512, 4) void gemm2(
    const bf16* __restrict__ hbuf, const bf16* __restrict__ w2t,
    const float* __restrict__ b2, const int* __restrict__ lists,
    const int* __restrict__ cnt, float* __restrict__ out) {
  int lin = blockIdx.x;
  int xcd = lin & 7;
  int rem = lin >> 3;
  int nc  = rem & (NC2 - 1);
  int rem2 = rem >> 1;
  int kh  = rem2 & (KSPLIT - 1);
  int rb  = (rem2 >> 1) * 8 + xcd;
  int e   = rb >> 6;
  int m0  = (rb & 63) * BM;
  int ce  = cnt[e];
  if (m0 >= ce) return;
  int n0 = nc * BN;
  int rbase = rowbase_of(cnt, e);

  __shared__ bf16 hs[2][BM * BK];
  __shared__ bf16 bs[2][BN * BK];
  __shared__ int tok[BM];

  int tid = threadIdx.x;
  if (tid < BM) {
    int r = m0 + tid;
    tok[tid] = (r < ce) ? lists[e * NTOK + r] : -1;
  }
  __syncthreads();

  const bf16* hbase = hbuf + (size_t)(rbase + m0) * H_DIM + kh * KHALF;
  const bf16* w2e = w2t + (size_t)e * H_DIM * D_DIM + (size_t)n0 * H_DIM + kh * KHALF;
  int wave = tid >> 6, lane = tid & 63;
  int quad = lane >> 4, l16 = lane & 15;
  int lr = lane >> 2;
  int ls = lane & 3;
  int srcoff = ((((ls ^ (lr & 3)) - ((lr >> 2) & 3)) & 3)) * 8;
  int wm = (wave >> 2) * 128, wn = (wave & 3) * 64;
  int rslot = (((quad + ((l16 >> 2) & 3)) & 3) ^ (l16 & 3)) * 8;

  const bf16* asrc[2]; const bf16* bsrc[2]; int soff[2];
  #pragma unroll
  for (int i = 0; i < 2; i++) {
    int s = wave * 2 + i;
    asrc[i] = hbase + (size_t)(s * 16 + lr) * H_DIM + srcoff;
    bsrc[i] = w2e + (size_t)(s * 16 + lr) * H_DIM + srcoff;
    soff[i] = s * 512;
  }
  auto stage = [&](int buf, int k0) {
    #pragma unroll
    for (int i = 0; i < 2; i++) gl_lds16(asrc[i] + k0, &hs[buf][soff[i]]);
    #pragma unroll
    for (int i = 0; i < 2; i++) gl_lds16(bsrc[i] + k0, &bs[buf][soff[i]]);
  };

  f32x4 acc[8][4] = {};
  const int nk = KHALF / BK;  // 32
  stage(0, 0);
  stage(1, BK);
  for (int t = 0; t < nk; t++) {
    if (t + 1 < nk) { asm volatile("s_waitcnt vmcnt(4)" ::: "memory"); }
    else            { asm volatile("s_waitcnt vmcnt(0)" ::: "memory"); }
    __builtin_amdgcn_sched_barrier(0);
    __builtin_amdgcn_s_barrier();
    __builtin_amdgcn_sched_barrier(0);
    const bf16* hsc = hs[t & 1];
    const bf16* bsc = bs[t & 1];
    __builtin_amdgcn_s_setprio(1);
    {
      bf16x8 bfr[4];
      #pragma unroll
      for (int j = 0; j < 4; j++)
        bfr[j] = *reinterpret_cast<const bf16x8*>(&bsc[(wn + j * 16 + l16) * BK + rslot]);
      #pragma unroll
      for (int i = 0; i < 8; i++) {
        bf16x8 af = *reinterpret_cast<const bf16x8*>(&hsc[(wm + i * 16 + l16) * BK + rslot]);
        #pragma unroll
        for (int j = 0; j < 4; j++)
          acc[i][j] = __builtin_amdgcn_mfma_f32_16x16x32_bf16(af, bfr[j], acc[i][j], 0, 0, 0);
      }
    }
    __builtin_amdgcn_s_setprio(0);
    __builtin_amdgcn_sched_barrier(0);
    __builtin_amdgcn_s_barrier();
    __builtin_amdgcn_sched_barrier(0);
    if (t + 2 < nk) stage(t & 1, (t + 2) * BK);
  }

  #pragma unroll
  for (int i = 0; i < 8; i++) {
    int row = wm + i * 16 + quad * 4;
    #pragma unroll
    for (int j = 0; j < 4; j++) {
      int col = n0 + wn + j * 16 + l16;
      float bias = (kh == 0) ? b2[e * D_DIM + col] : 0.0f;
      #pragma unroll
      for (int r = 0; r < 4; r++) {
        int t = tok[row + r];
        if (t >= 0) {
          float v = 0.5f * (acc[i][j][r] + bias);
          atomicAdd(&out[(size_t)t * D_DIM + col], v);
        }
      }
    }
  }
}

// ---------------- launch ----------------
extern "C" void kernel_launch(void* const* d_in, const int* in_sizes, int n_in,
                              void* d_out, int out_size, void* d_ws, size_t ws_size,
                              hipStream_t stream) {
  const float* x      = (const float*)d_in[0];
  const int*   assign = (const int*)d_in[1];
  const float* W1     = (const float*)d_in[2];
  const float* b1     = (const float*)d_in[3];
  const float* W2     = (const float*)d_in[4];
  const float* b2     = (const float*)d_in[5];
  float* out = (float*)d_out;
  char* ws = (char*)d_ws;

  int* fill    = (int*)(ws + OFF_FILL);
  int* lists   = (int*)(ws + OFF_LIST);
  bf16* xbf    = (bf16*)(ws + OFF_XBF);
  bf16* w1t    = (bf16*)(ws + OFF_W1T);
  bf16* w2t    = (bf16*)(ws + OFF_W2T);
  bf16* hbuf   = (bf16*)(ws + OFF_HBUF);

  hipMemsetAsync(ws, 0, 128, stream);
  hipMemsetAsync(d_out, 0, (size_t)out_size * sizeof(float), stream);

  fill_kernel<<<NTOK / 256, 256, 0, stream>>>(assign, fill, lists);

  cvt_x<<<(NTOK * D_DIM) / (256 * 8), 256, 0, stream>>>(x, xbf);
  // W1 [E][D][H] -> W1T [E][H][D];  W2 [E][H][D] -> W2T [E][D][H]
  transpose_cvt<<<dim3(H_DIM / 32, D_DIM / 32, E_NUM), dim3(32, 8), 0, stream>>>(W1, w1t, D_DIM, H_DIM);
  transpose_cvt<<<dim3(D_DIM / 32, H_DIM / 32, E_NUM), dim3(32, 8), 0, stream>>>(W2, w2t, H_DIM, D_DIM);

  // 1D swizzled grids
  gemm1<<<(E_NUM * NTOK / BM) * NC1, 512, 0, stream>>>(xbf, w1t, b1, lists, fill, hbuf);
  gemm2<<<(E_NUM * NTOK / BM) * NC2 * KSPLIT, 512, 0, stream>>>(hbuf, w2t, b2, lists, fill, out);

  (void)in_sizes; (void)n_in; (void)ws_size;
}

// Round 16
// 376.798 us; speedup vs baseline: 3.4730x; 3.4730x over previous
//
#include <hip/hip_runtime.h>
#include <hip/hip_bf16.h>
#include <stdint.h>

// Problem constants
#define E_NUM 8
#define D_DIM 512
#define H_DIM 2048
#define NTOK 16384   // B*S = 8*2048

typedef __bf16 bf16;
typedef __bf16 bf16x8 __attribute__((ext_vector_type(8)));
typedef float  f32x4  __attribute__((ext_vector_type(4)));

// r13 base (381us, best): 256x256 tile, BK=64, 8 waves, counted-vmcnt v2 loop
// (unfenced read+MFMA, vmcnt(8) arrival wait, depth-2 staging, T2 dual-side swizzle).
// r15 lessons: NO K-split (cross-XCD atomic line ping-pong: WRITE 61->939MB), NO
// BK=32 (64B strided fetches below DRAM granularity). This round adds only:
//  (a) gemm1 epilogue restaged through LDS -> 16B/lane coalesced stores
//      (fixes 1.84x write amplification: 232MB -> ~128MB)
//  (b) fused prep kernels (8 -> 6 dispatches)
#define BM 256
#define BN 256
#define BK 64

// async global->LDS, 16B per lane
typedef __attribute__((address_space(1))) const void* gas_cp;
typedef __attribute__((address_space(3))) void* las_p;
__device__ __forceinline__ void gl_lds16(const void* g, void* l) {
  __builtin_amdgcn_global_load_lds((gas_cp)g, (las_p)l, 16, 0, 0);
}

// Workspace layout (bytes)
static const size_t OFF_FILL = 32;           // 8 ints (per-expert count after fill)
static const size_t OFF_LIST = 128;          // E*NTOK ints = 512KB
static const size_t OFF_XBF  = 1ull << 20;                              // bf16 [NTOK][D] = 16.8MB
static const size_t OFF_W1T  = OFF_XBF + (size_t)NTOK*D_DIM*2;          // bf16 [E][H][D]
static const size_t OFF_W2T  = OFF_W1T + (size_t)E_NUM*H_DIM*D_DIM*2;   // bf16 [E][D][H]
static const size_t OFF_HBUF = OFF_W2T + (size_t)E_NUM*H_DIM*D_DIM*2;   // bf16 [<=34816][H] (256-pad)

// rowbase for expert e, computed from counts (all blocks agree; cnt final at kernel launch)
__device__ __forceinline__ int rowbase_of(const int* cnt, int e) {
  int acc = 0;
  for (int i = 0; i < e; i++) acc += (cnt[i] + BM - 1) & ~(BM - 1);
  return acc;
}

// ---------------- prep: x f32->bf16 cvt (all blocks) + routing fill (first 64) ----------------
__global__ void prep_kernel(const float* __restrict__ x, bf16* __restrict__ xbf,
                            const int* __restrict__ assign, int* __restrict__ fill,
                            int* __restrict__ lists) {
  int gid = blockIdx.x * 256 + threadIdx.x;
  size_t i = (size_t)gid * 8;
  float4 a = *reinterpret_cast<const float4*>(x + i);
  float4 b = *reinterpret_cast<const float4*>(x + i + 4);
  bf16x8 o;
  o[0] = (bf16)a.x; o[1] = (bf16)a.y; o[2] = (bf16)a.z; o[3] = (bf16)a.w;
  o[4] = (bf16)b.x; o[5] = (bf16)b.y; o[6] = (bf16)b.z; o[7] = (bf16)b.w;
  *reinterpret_cast<bf16x8*>(xbf + i) = o;

  if (blockIdx.x < NTOK / 256) {   // wave-uniform: whole block does fill for tokens gid
    int n = gid;
    int lane = threadIdx.x & 63;
    unsigned long long below = ((unsigned long long)1 << lane) - 1;
    int e0 = assign[2*n], e1 = assign[2*n+1];
    #pragma unroll
    for (int e = 0; e < E_NUM; e++) {
      bool h0 = (e0 == e);
      bool h1 = (e1 == e) && (e1 != e0);
      unsigned long long m0 = __ballot(h0);
      unsigned long long m1 = __ballot(h1);
      int c = __popcll(m0) + __popcll(m1);
      if (c > 0) {                                   // wave-uniform
        int leader = __ffsll((long long)(m0 | m1)) - 1;
        int b2 = 0;
        if (lane == leader) b2 = atomicAdd(&fill[e], c);
        b2 = __shfl(b2, leader);
        if (h0) lists[e * NTOK + b2 + __popcll(m0 & below)] = n;
        if (h1) lists[e * NTOK + b2 + __popcll(m0) + __popcll(m1 & below)] = n;
      }
    }
  }
}

// ---------------- fused weight transposes: W1 and W2 in one launch ----------------
// W1 [E][D][H] -> w1t [E][H][D];  W2 [E][H][D] -> w2t [E][D][H]
#define T1_TILES (E_NUM * (H_DIM/32) * (D_DIM/32))   // 8192
__global__ void transpose_cvt2(const float* __restrict__ W1, bf16* __restrict__ w1t,
                               const float* __restrict__ W2, bf16* __restrict__ w2t) {
  __shared__ float tile[32][33];
  int bid = blockIdx.x;
  const float* in; bf16* out; int R, C, bx, by, e;
  if (bid < T1_TILES) {            // W1: R=D rows, C=H cols; per-expert 64x16 tiles
    e = bid >> 10; int rem = bid & 1023;
    bx = rem & 63; by = rem >> 6;
    in = W1; out = w1t; R = D_DIM; C = H_DIM;
  } else {                          // W2: R=H rows, C=D cols; per-expert 16x64 tiles
    int b2 = bid - T1_TILES;
    e = b2 >> 10; int rem = b2 & 1023;
    bx = rem & 15; by = rem >> 4;
    in = W2; out = w2t; R = H_DIM; C = D_DIM;
  }
  int c0 = bx * 32, r0 = by * 32;
  const float* src = in + (size_t)e * R * C;
  bf16* dst = out + (size_t)e * R * C;
  int tx = threadIdx.x, ty = threadIdx.y;  // 32 x 8
  #pragma unroll
  for (int i = 0; i < 32; i += 8)
    tile[ty + i][tx] = src[(size_t)(r0 + ty + i) * C + c0 + tx];
  __syncthreads();
  #pragma unroll
  for (int i = 0; i < 32; i += 8)
    dst[(size_t)(c0 + ty + i) * R + r0 + tx] = (bf16)tile[tx][ty + i];
}

// ---------------- GEMM1: h = relu(Xg @ W1 + b1), bf16 out to hbuf ----------------
// grid: 1D, lin = xcd + 8*(nc + NC1*rbHi); rb = rbHi*8 + xcd; NC1 = 8 chunks over H
#define NC1 (H_DIM / BN)   // 8
__global__ __launch_bounds__(512, 2) void gemm1(
    const bf16* __restrict__ xbf, const bf16* __restrict__ w1t,
    const float* __restrict__ b1, const int* __restrict__ lists,
    const int* __restrict__ cnt, bf16* __restrict__ hbuf) {
  int lin = blockIdx.x;
  int xcd = lin & 7;
  int rem = lin >> 3;
  int nc  = rem & (NC1 - 1);
  int rb  = (rem >> 3) * 8 + xcd;          // rem >> log2(NC1)
  int e   = rb >> 6;                        // rb / 64 (64 row-blocks of 256 per expert)
  int m0  = (rb & 63) * BM;
  int ce  = cnt[e];
  if (m0 >= ce) return;
  int n0 = nc * BN;
  int rbase = rowbase_of(cnt, e);

  // single 128KB arena: staging dbuf in K-loop, C-tile in epilogue
  __shared__ bf16 smem[2 * BM * BK + 2 * BN * BK];   // 65536 elems
  __shared__ int tok[BM];

  int tid = threadIdx.x;
  if (tid < BM) {
    int r = m0 + tid;
    tok[tid] = (r < ce) ? lists[e * NTOK + r] : lists[e * NTOK];
  }
  __syncthreads();

  const bf16* w1e = w1t + (size_t)e * H_DIM * D_DIM + (size_t)n0 * D_DIM;
  int wave = tid >> 6, lane = tid & 63;
  int quad = lane >> 4, l16 = lane & 15;
  int lr = lane >> 3;                        // staging: row within 8-row segment
  int lcs = (((lane & 7) ^ lr)) * 8;         // SWIZZLED source col-slot (elements)
  int wm = (wave >> 2) * 128, wn = (wave & 3) * 64;   // 2M x 4N wave grid
  int l7 = l16 & 7;                          // read-side swizzle key (== row&7)

  const bf16* asrc[4]; const bf16* bsrc[4]; int soff[4];
  #pragma unroll
  for (int i = 0; i < 4; i++) {
    int s = wave * 4 + i;                    // segment: rows [8s, 8s+8)
    asrc[i] = xbf + (size_t)tok[s * 8 + lr] * D_DIM + lcs;
    bsrc[i] = w1e + (size_t)(s * 8 + lr) * D_DIM + lcs;
    soff[i] = s * 512;
  }
  auto stage = [&](int buf, int k0) {
    bf16* xsb = smem + buf * (BM * BK);
    bf16* bsb = smem + 2 * (BM * BK) + buf * (BN * BK);
    #pragma unroll
    for (int i = 0; i < 4; i++) gl_lds16(asrc[i] + k0, xsb + soff[i]);
    #pragma unroll
    for (int i = 0; i < 4; i++) gl_lds16(bsrc[i] + k0, bsb + soff[i]);
  };

  f32x4 acc[8][4] = {};
  const int nk = D_DIM / BK;  // 8
  stage(0, 0);
  stage(1, BK);
  for (int t = 0; t < nk; t++) {
    if (t + 1 < nk) { asm volatile("s_waitcnt vmcnt(8)" ::: "memory"); }
    else            { asm volatile("s_waitcnt vmcnt(0)" ::: "memory"); }
    __builtin_amdgcn_sched_barrier(0);
    __builtin_amdgcn_s_barrier();            // buf[t&1] ready for all waves
    __builtin_amdgcn_sched_barrier(0);
    const bf16* xsc = smem + (t & 1) * (BM * BK);
    const bf16* bsc = smem + 2 * (BM * BK) + (t & 1) * (BN * BK);
    // read + MFMA, UNFENCED: compiler emits fine-grained lgkmcnt interleave (m97)
    __builtin_amdgcn_s_setprio(1);
    #pragma unroll
    for (int k2 = 0; k2 < 2; k2++) {
      int sw = ((quad + k2 * 4) ^ l7) * 8;   // swizzled slot offset (elements)
      bf16x8 bfr[4];
      #pragma unroll
      for (int j = 0; j < 4; j++)
        bfr[j] = *reinterpret_cast<const bf16x8*>(&bsc[(wn + j * 16 + l16) * BK + sw]);
      #pragma unroll
      for (int i = 0; i < 8; i++) {
        bf16x8 af = *reinterpret_cast<const bf16x8*>(&xsc[(wm + i * 16 + l16) * BK + sw]);
        #pragma unroll
        for (int j = 0; j < 4; j++)
          acc[i][j] = __builtin_amdgcn_mfma_f32_16x16x32_bf16(af, bfr[j], acc[i][j], 0, 0, 0);
      }
    }
    __builtin_amdgcn_s_setprio(0);
    __builtin_amdgcn_sched_barrier(0);
    __builtin_amdgcn_s_barrier();            // all waves consumed buf[t&1] (reads in regs)
    __builtin_amdgcn_sched_barrier(0);
    if (t + 2 < nk) stage(t & 1, (t + 2) * BK);   // overwrite freed buf; flies across next vmcnt(8)
  }

  // ---- epilogue: bias+relu, C through LDS (slot-XOR), coalesced 16B stores ----
  // After the loop's final barrier all LDS reads are consumed -> smem reusable.
  {
    bf16* cs = smem;   // C[256][256] bf16 = 128KB, elem (row, col^((row&7)<<3))
    #pragma unroll
    for (int i = 0; i < 8; i++) {
      int row = wm + i * 16 + quad * 4;
      #pragma unroll
      for (int j = 0; j < 4; j++) {
        int col = wn + j * 16 + l16;
        float bias = b1[e * H_DIM + n0 + col];
        #pragma unroll
        for (int r = 0; r < 4; r++) {
          float v = acc[i][j][r] + bias;
          v = v > 0.f ? v : 0.f;
          int rw = row + r;
          cs[rw * 256 + (col ^ ((rw & 7) << 3))] = (bf16)v;
        }
      }
    }
    __syncthreads();
    bf16* hb = hbuf + (size_t)(rbase + m0) * H_DIM + n0;
    int rr = tid >> 5;            // 0..15
    int sl = tid & 31;            // 16B slot within row
    #pragma unroll
    for (int p = 0; p < 16; p++) {
      int row = p * 16 + rr;
      *reinterpret_cast<bf16x8*>(hb + (size_t)row * H_DIM + sl * 8) =
        *reinterpret_cast<const bf16x8*>(&cs[row * 256 + ((sl ^ (row & 7)) * 8)]);
    }
  }
}

// ---------------- GEMM2: out += 0.5*(h @ W2 + b2), scattered fp32 atomicAdd ----------------
// r13 form exactly: no K-split (r15: cross-XCD atomic ping-pong), NC2 = 2 chunks over D
#define NC2 (D_DIM / BN)   // 2
__global__ __launch_bounds__(512, 2) void gemm2(
    const bf16* __restrict__ hbuf, const bf16* __restrict__ w2t,
    const float* __restrict__ b2, const int* __restrict__ lists,
    const int* __restrict__ cnt, float* __restrict__ out) {
  int lin = blockIdx.x;
  int xcd = lin & 7;
  int rem = lin >> 3;
  int nc  = rem & (NC2 - 1);
  int rb  = (rem >> 1) * 8 + xcd;
  int e   = rb >> 6;
  int m0  = (rb & 63) * BM;
  int ce  = cnt[e];
  if (m0 >= ce) return;
  int n0 = nc * BN;
  int rbase = rowbase_of(cnt, e);

  __shared__ bf16 hs[2][BM * BK];
  __shared__ bf16 bs[2][BN * BK];
  __shared__ int tok[BM];

  int tid = threadIdx.x;
  if (tid < BM) {
    int r = m0 + tid;
    tok[tid] = (r < ce) ? lists[e * NTOK + r] : -1;
  }
  __syncthreads();

  const bf16* hbase = hbuf + (size_t)(rbase + m0) * H_DIM;
  const bf16* w2e = w2t + (size_t)e * H_DIM * D_DIM + (size_t)n0 * H_DIM;
  int wave = tid >> 6, lane = tid & 63;
  int quad = lane >> 4, l16 = lane & 15;
  int lr = lane >> 3;
  int lcs = (((lane & 7) ^ lr)) * 8;         // SWIZZLED source col-slot (elements)
  int wm = (wave >> 2) * 128, wn = (wave & 3) * 64;
  int l7 = l16 & 7;

  const bf16* asrc[4]; const bf16* bsrc[4]; int soff[4];
  #pragma unroll
  for (int i = 0; i < 4; i++) {
    int s = wave * 4 + i;
    asrc[i] = hbase + (size_t)(s * 8 + lr) * H_DIM + lcs;
    bsrc[i] = w2e + (size_t)(s * 8 + lr) * H_DIM + lcs;
    soff[i] = s * 512;
  }
  auto stage = [&](int buf, int k0) {
    #pragma unroll
    for (int i = 0; i < 4; i++) gl_lds16(asrc[i] + k0, &hs[buf][soff[i]]);
    #pragma unroll
    for (int i = 0; i < 4; i++) gl_lds16(bsrc[i] + k0, &bs[buf][soff[i]]);
  };

  f32x4 acc[8][4] = {};
  const int nk = H_DIM / BK;  // 32
  stage(0, 0);
  stage(1, BK);
  for (int t = 0; t < nk; t++) {
    if (t + 1 < nk) { asm volatile("s_waitcnt vmcnt(8)" ::: "memory"); }
    else            { asm volatile("s_waitcnt vmcnt(0)" ::: "memory"); }
    __builtin_amdgcn_sched_barrier(0);
    __builtin_amdgcn_s_barrier();
    __builtin_amdgcn_sched_barrier(0);
    const bf16* hsc = hs[t & 1];
    const bf16* bsc = bs[t & 1];
    __builtin_amdgcn_s_setprio(1);
    #pragma unroll
    for (int k2 = 0; k2 < 2; k2++) {
      int sw = ((quad + k2 * 4) ^ l7) * 8;
      bf16x8 bfr[4];
      #pragma unroll
      for (int j = 0; j < 4; j++)
        bfr[j] = *reinterpret_cast<const bf16x8*>(&bsc[(wn + j * 16 + l16) * BK + sw]);
      #pragma unroll
      for (int i = 0; i < 8; i++) {
        bf16x8 af = *reinterpret_cast<const bf16x8*>(&hsc[(wm + i * 16 + l16) * BK + sw]);
        #pragma unroll
        for (int j = 0; j < 4; j++)
          acc[i][j] = __builtin_amdgcn_mfma_f32_16x16x32_bf16(af, bfr[j], acc[i][j], 0, 0, 0);
      }
    }
    __builtin_amdgcn_s_setprio(0);
    __builtin_amdgcn_sched_barrier(0);
    __builtin_amdgcn_s_barrier();
    __builtin_amdgcn_sched_barrier(0);
    if (t + 2 < nk) stage(t & 1, (t + 2) * BK);
  }

  #pragma unroll
  for (int i = 0; i < 8; i++) {
    int row = wm + i * 16 + quad * 4;
    #pragma unroll
    for (int j = 0; j < 4; j++) {
      int col = n0 + wn + j * 16 + l16;
      float bias = b2[e * D_DIM + col];
      #pragma unroll
      for (int r = 0; r < 4; r++) {
        int t = tok[row + r];
        if (t >= 0) {
          float v = 0.5f * (acc[i][j][r] + bias);
          atomicAdd(&out[(size_t)t * D_DIM + col], v);
        }
      }
    }
  }
}

// ---------------- launch ----------------
extern "C" void kernel_launch(void* const* d_in, const int* in_sizes, int n_in,
                              void* d_out, int out_size, void* d_ws, size_t ws_size,
                              hipStream_t stream) {
  const float* x      = (const float*)d_in[0];
  const int*   assign = (const int*)d_in[1];
  const float* W1     = (const float*)d_in[2];
  const float* b1     = (const float*)d_in[3];
  const float* W2     = (const float*)d_in[4];
  const float* b2     = (const float*)d_in[5];
  float* out = (float*)d_out;
  char* ws = (char*)d_ws;

  int* fill    = (int*)(ws + OFF_FILL);
  int* lists   = (int*)(ws + OFF_LIST);
  bf16* xbf    = (bf16*)(ws + OFF_XBF);
  bf16* w1t    = (bf16*)(ws + OFF_W1T);
  bf16* w2t    = (bf16*)(ws + OFF_W2T);
  bf16* hbuf   = (bf16*)(ws + OFF_HBUF);

  hipMemsetAsync(ws, 0, 128, stream);
  hipMemsetAsync(d_out, 0, (size_t)out_size * sizeof(float), stream);

  prep_kernel<<<(NTOK * D_DIM) / (256 * 8), 256, 0, stream>>>(x, xbf, assign, fill, lists);
  transpose_cvt2<<<2 * T1_TILES, dim3(32, 8), 0, stream>>>(W1, w1t, W2, w2t);

  // 1D swizzled grids: total = (E*NTOK/BM) * NC, encode lin = xcd + 8*(nc + NC*rbHi)
  gemm1<<<(E_NUM * NTOK / BM) * NC1, 512, 0, stream>>>(xbf, w1t, b1, lists, fill, hbuf);
  gemm2<<<(E_NUM * NTOK / BM) * NC2, 512, 0, stream>>>(hbuf, w2t, b2, lists, fill, out);

  (void)in_sizes; (void)n_in; (void)ws_size;
}